// Round 1
// baseline (4438.734 us; speedup 1.0000x reference)
//
#include <hip/hip_runtime.h>
#include <math.h>

// Problem dims (fixed by reference)
#define SEQ   128
#define BATCH 64
#define HD    1024     // I == H == O == 1024
#define NG    4096     // 4*H
#define TOUT  32
#define KS    8        // split-K slices

// ---------------------------------------------------------------------------
// Split-K tiled fp32 GEMM:  Cpart[z] += A_pair[64 x klen] * B_pair[64cols x klen]^T
// C tile: 64 rows (batch) x 64 cols.  grid = (N/64, KS), block = 256.
// If A2 != null: two (A,B) pairs, 4 slices each (z>>2 selects pair).
// Else: one pair, 8 slices.
// Cpart layout: [KS][64][N]
// ---------------------------------------------------------------------------
__global__ __launch_bounds__(256) void gemm_splitk(
    const float* __restrict__ A1, const float* __restrict__ B1,
    const float* __restrict__ A2, const float* __restrict__ B2,
    float* __restrict__ Cpart, int N, int K)
{
    const int z = blockIdx.y;
    int pair, k0, klen;
    if (A2) { pair = z >> 2; klen = K >> 2; k0 = (z & 3) * klen; }
    else    { pair = 0;      klen = K >> 3; k0 = z * klen; }
    const float* __restrict__ A = pair ? A2 : A1;
    const float* __restrict__ B = pair ? B2 : B1;

    __shared__ float As[32][68];   // [k][row], pad 68 keeps float4 reads aligned
    __shared__ float Bs[32][68];

    const int tid = threadIdx.x;
    const int jt  = blockIdx.x * 64;      // output col tile base
    const int lr  = tid >> 2;             // load row 0..63
    const int lc  = (tid & 3) * 8;        // load k-offset {0,8,16,24}

    const int ry = (tid >> 4) * 4;        // micro-tile row base (0..60)
    const int cx = (tid & 15) * 4;        // micro-tile col base (0..60)

    float acc[4][4] = {{0.f}};

    for (int kt = 0; kt < klen; kt += 32) {
        const float* ap = A + (size_t)lr * K + k0 + kt + lc;
        const float* bp = B + (size_t)(jt + lr) * K + k0 + kt + lc;
        float4 a0 = *(const float4*)ap;
        float4 a1 = *(const float4*)(ap + 4);
        float4 b0 = *(const float4*)bp;
        float4 b1 = *(const float4*)(bp + 4);
        __syncthreads();  // previous tile fully consumed
        As[lc+0][lr] = a0.x; As[lc+1][lr] = a0.y; As[lc+2][lr] = a0.z; As[lc+3][lr] = a0.w;
        As[lc+4][lr] = a1.x; As[lc+5][lr] = a1.y; As[lc+6][lr] = a1.z; As[lc+7][lr] = a1.w;
        Bs[lc+0][lr] = b0.x; Bs[lc+1][lr] = b0.y; Bs[lc+2][lr] = b0.z; Bs[lc+3][lr] = b0.w;
        Bs[lc+4][lr] = b1.x; Bs[lc+5][lr] = b1.y; Bs[lc+6][lr] = b1.z; Bs[lc+7][lr] = b1.w;
        __syncthreads();
        #pragma unroll
        for (int k = 0; k < 32; k++) {
            float4 av = *(const float4*)&As[k][ry];
            float4 bv = *(const float4*)&Bs[k][cx];
            acc[0][0] += av.x*bv.x; acc[0][1] += av.x*bv.y; acc[0][2] += av.x*bv.z; acc[0][3] += av.x*bv.w;
            acc[1][0] += av.y*bv.x; acc[1][1] += av.y*bv.y; acc[1][2] += av.y*bv.z; acc[1][3] += av.y*bv.w;
            acc[2][0] += av.z*bv.x; acc[2][1] += av.z*bv.y; acc[2][2] += av.z*bv.z; acc[2][3] += av.z*bv.w;
            acc[3][0] += av.w*bv.x; acc[3][1] += av.w*bv.y; acc[3][2] += av.w*bv.z; acc[3][3] += av.w*bv.w;
        }
    }

    #pragma unroll
    for (int i = 0; i < 4; i++) {
        float4 v = make_float4(acc[i][0], acc[i][1], acc[i][2], acc[i][3]);
        *(float4*)&Cpart[(size_t)(z * 64 + ry + i) * N + jt + cx] = v;
    }
}

// ---------------------------------------------------------------------------
// LSTM pointwise: sum KS gate partials + biases, apply activations, update c,h.
// gp: [KS][64][4096]
// ---------------------------------------------------------------------------
__global__ __launch_bounds__(256) void lstm_pointwise(
    const float* __restrict__ gp,
    const float* __restrict__ b_ih, const float* __restrict__ b_hh,
    float* __restrict__ c, float* __restrict__ h)
{
    const int idx = blockIdx.x * 256 + threadIdx.x;   // 0..65535
    const int b = idx >> 10;
    const int j = idx & 1023;
    const float* g0 = gp + (size_t)b * NG;
    float ig = 0.f, fg = 0.f, gg = 0.f, og = 0.f;
    #pragma unroll
    for (int z = 0; z < KS; z++) {
        const float* g = g0 + (size_t)z * 64 * NG;
        ig += g[j];
        fg += g[j + 1024];
        gg += g[j + 2048];
        og += g[j + 3072];
    }
    ig += b_ih[j]        + b_hh[j];
    fg += b_ih[j + 1024] + b_hh[j + 1024];
    gg += b_ih[j + 2048] + b_hh[j + 2048];
    og += b_ih[j + 3072] + b_hh[j + 3072];

    const float si = 1.f / (1.f + expf(-ig));
    const float sf = 1.f / (1.f + expf(-fg));
    const float so = 1.f / (1.f + expf(-og));
    const float tg = tanhf(gg);
    const float cn = sf * c[idx] + si * tg;
    c[idx] = cn;
    h[idx] = so * tanhf(cn);
}

// ---------------------------------------------------------------------------
// Projection epilogue: sum KS partials + bias, row-wise log_softmax, write out.
// lp: [KS][64][1024];  out: [64][1024]
// ---------------------------------------------------------------------------
__global__ __launch_bounds__(256) void proj_softmax(
    const float* __restrict__ lp,
    const float* __restrict__ b_out,
    float* __restrict__ out)
{
    const int b = blockIdx.x;
    __shared__ float row[1024];
    __shared__ float red[256];
    const int tid = threadIdx.x;

    for (int j = tid; j < 1024; j += 256) {
        float v = b_out[j];
        #pragma unroll
        for (int z = 0; z < KS; z++)
            v += lp[(size_t)(z * 64 + b) * 1024 + j];
        row[j] = v;
    }
    __syncthreads();

    float m = -INFINITY;
    for (int j = tid; j < 1024; j += 256) m = fmaxf(m, row[j]);
    red[tid] = m; __syncthreads();
    for (int st = 128; st > 0; st >>= 1) {
        if (tid < st) red[tid] = fmaxf(red[tid], red[tid + st]);
        __syncthreads();
    }
    m = red[0];
    __syncthreads();

    float s = 0.f;
    for (int j = tid; j < 1024; j += 256) s += expf(row[j] - m);
    red[tid] = s; __syncthreads();
    for (int st = 128; st > 0; st >>= 1) {
        if (tid < st) red[tid] += red[tid + st];
        __syncthreads();
    }
    const float lse = m + logf(red[0]);

    for (int j = tid; j < 1024; j += 256)
        out[(size_t)b * 1024 + j] = row[j] - lse;
}

// ---------------------------------------------------------------------------
// Copy two buffers (init h/c, final h/c write-out)
// ---------------------------------------------------------------------------
__global__ __launch_bounds__(256) void copy2(
    const float* __restrict__ a, const float* __restrict__ b,
    float* __restrict__ da, float* __restrict__ db, int n)
{
    const int i = blockIdx.x * 256 + threadIdx.x;
    if (i < n) { da[i] = a[i]; db[i] = b[i]; }
}

// ---------------------------------------------------------------------------
extern "C" void kernel_launch(void* const* d_in, const int* in_sizes, int n_in,
                              void* d_out, int out_size, void* d_ws, size_t ws_size,
                              hipStream_t stream)
{
    const float* input = (const float*)d_in[0];   // [128,64,1024]
    const float* h0    = (const float*)d_in[1];   // [1,64,1024]
    const float* c0    = (const float*)d_in[2];
    const float* W_ih  = (const float*)d_in[3];   // [4096,1024]
    const float* W_hh  = (const float*)d_in[4];   // [4096,1024]
    const float* b_ih  = (const float*)d_in[5];   // [4096]
    const float* b_hh  = (const float*)d_in[6];
    const float* W_out = (const float*)d_in[7];   // [1024,1024]
    const float* b_out = (const float*)d_in[8];   // [1024]
    float* out = (float*)d_out;                   // [32,64,1024] + h[64,1024] + c[64,1024]

    float* ws    = (float*)d_ws;
    float* gpart = ws;                              // KS*64*4096 = 2,097,152 floats
    float* hbuf  = gpart + (size_t)KS * 64 * NG;    // 65536
    float* cbuf  = hbuf + BATCH * HD;               // 65536
    float* ppart = cbuf + BATCH * HD;               // KS*64*1024 = 524,288 floats

    const int NE = BATCH * HD;  // 65536

    // init recurrent state
    copy2<<<dim3(NE / 256), dim3(256), 0, stream>>>(h0, c0, hbuf, cbuf, NE);

    // ---- encode: 128 steps ----
    for (int t = 0; t < SEQ; t++) {
        gemm_splitk<<<dim3(NG / 64, KS), dim3(256), 0, stream>>>(
            input + (size_t)t * NE, W_ih, hbuf, W_hh, gpart, NG, HD);
        lstm_pointwise<<<dim3(NE / 256), dim3(256), 0, stream>>>(
            gpart, b_ih, b_hh, cbuf, hbuf);
    }

    // out0 = log_softmax(h @ W_out^T + b_out)
    gemm_splitk<<<dim3(HD / 64, KS), dim3(256), 0, stream>>>(
        hbuf, W_out, nullptr, nullptr, ppart, HD, HD);
    proj_softmax<<<dim3(BATCH), dim3(256), 0, stream>>>(ppart, b_out, out);

    // ---- decode: 31 steps, feeding previous log-softmax output back ----
    for (int d = 1; d < TOUT; d++) {
        gemm_splitk<<<dim3(NG / 64, KS), dim3(256), 0, stream>>>(
            out + (size_t)(d - 1) * NE, W_ih, hbuf, W_hh, gpart, NG, HD);
        lstm_pointwise<<<dim3(NE / 256), dim3(256), 0, stream>>>(
            gpart, b_ih, b_hh, cbuf, hbuf);
        gemm_splitk<<<dim3(HD / 64, KS), dim3(256), 0, stream>>>(
            hbuf, W_out, nullptr, nullptr, ppart, HD, HD);
        proj_softmax<<<dim3(BATCH), dim3(256), 0, stream>>>(ppart, b_out, out + (size_t)d * NE);
    }

    // final h, c
    copy2<<<dim3(NE / 256), dim3(256), 0, stream>>>(
        hbuf, cbuf, out + (size_t)TOUT * NE, out + (size_t)(TOUT + 1) * NE, NE);
}

// Round 2
// 3241.134 us; speedup vs baseline: 1.3695x; 1.3695x over previous
//
#include <hip/hip_runtime.h>
#include <math.h>

// Problem dims (fixed by reference)
#define SEQ   128
#define BATCH 64
#define HD    1024     // I == H == O == 1024
#define NG    4096     // 4*H
#define TOUT  32
#define CH    16       // encode chunk (steps) for hoisted x@W_ih^T

typedef __attribute__((ext_vector_type(8))) short short8;
typedef __attribute__((ext_vector_type(4))) float f32x4;

__device__ inline ushort bf16_rne(float x) {
    union { float f; unsigned u; } v; v.f = x;
    unsigned r = v.u + 0x7FFF + ((v.u >> 16) & 1);
    return (ushort)(r >> 16);
}

// ---------------------------------------------------------------------------
// fp32 -> bf16 (RNE), vectorized x4. n must be a multiple of 4.
// ---------------------------------------------------------------------------
__global__ __launch_bounds__(256) void f32_to_bf16(
    const float* __restrict__ src, ushort* __restrict__ dst, int n)
{
    int i = (blockIdx.x * 256 + threadIdx.x) * 4;
    if (i < n) {
        float4 v = *(const float4*)(src + i);
        ushort4 o;
        o.x = bf16_rne(v.x); o.y = bf16_rne(v.y);
        o.z = bf16_rne(v.z); o.w = bf16_rne(v.w);
        *(ushort4*)(dst + i) = o;
    }
}

// ---------------------------------------------------------------------------
// init: h=h0, c=c0, h_bf=bf16(h0)
// ---------------------------------------------------------------------------
__global__ __launch_bounds__(256) void init_state(
    const float* __restrict__ h0, const float* __restrict__ c0,
    float* __restrict__ h, float* __restrict__ c, ushort* __restrict__ h_bf)
{
    int i = blockIdx.x * 256 + threadIdx.x;
    float hv = h0[i];
    h[i] = hv; c[i] = c0[i]; h_bf[i] = bf16_rne(hv);
}

// ---------------------------------------------------------------------------
// MFMA bf16 GEMM, B transposed (both A and B stored row-major [rows][K=1024]).
// C[m][n] = sum_k A[m][k] * B[n][k], fp32 accum, LDS-free direct fragment loads.
// grid = (N/64, M/64, Z).  block = 256 (4 waves; wave w -> 16-row slab).
// Split-K: slice z covers k0 = z*ksl .. +ksl.  If A2 != null: z in [4,8) uses
// (A2,B2) with k0=(z-4)*ksl (dual-pair mode for decode gates).
// C layout: [Z][M][N] (Z=1, A2=null for the plain case).
// K pitch is hard-coded 1024 (all GEMMs here have K=1024).
// ---------------------------------------------------------------------------
__global__ __launch_bounds__(256) void gemm_bt_mfma(
    const ushort* __restrict__ A1, const ushort* __restrict__ B1,
    const ushort* __restrict__ A2, const ushort* __restrict__ B2,
    float* __restrict__ C, int N, int ksl, int M)
{
    const int z = blockIdx.z;
    const ushort* __restrict__ A;
    const ushort* __restrict__ B;
    int k0;
    if (A2 && z >= 4) { A = A2; B = B2; k0 = (z - 4) * ksl; }
    else             { A = A1; B = B1; k0 = z * ksl; }

    const int wave = threadIdx.x >> 6;
    const int lane = threadIdx.x & 63;
    const int l15  = lane & 15;
    const int q8   = (lane >> 4) * 8;          // k sub-offset for frags
    const int mrow = blockIdx.y * 64 + wave * 16 + l15;
    const int nbase = blockIdx.x * 64;

    const ushort* ap = A + (size_t)mrow * 1024 + k0 + q8;
    const ushort* bp0 = B + (size_t)(nbase + 0 * 16 + l15) * 1024 + k0 + q8;
    const ushort* bp1 = B + (size_t)(nbase + 1 * 16 + l15) * 1024 + k0 + q8;
    const ushort* bp2 = B + (size_t)(nbase + 2 * 16 + l15) * 1024 + k0 + q8;
    const ushort* bp3 = B + (size_t)(nbase + 3 * 16 + l15) * 1024 + k0 + q8;

    f32x4 acc0 = {0.f, 0.f, 0.f, 0.f};
    f32x4 acc1 = {0.f, 0.f, 0.f, 0.f};
    f32x4 acc2 = {0.f, 0.f, 0.f, 0.f};
    f32x4 acc3 = {0.f, 0.f, 0.f, 0.f};

    for (int kk = 0; kk < ksl; kk += 32) {
        short8 av = *(const short8*)(ap + kk);
        short8 b0 = *(const short8*)(bp0 + kk);
        short8 b1 = *(const short8*)(bp1 + kk);
        short8 b2 = *(const short8*)(bp2 + kk);
        short8 b3 = *(const short8*)(bp3 + kk);
        acc0 = __builtin_amdgcn_mfma_f32_16x16x32_bf16(av, b0, acc0, 0, 0, 0);
        acc1 = __builtin_amdgcn_mfma_f32_16x16x32_bf16(av, b1, acc1, 0, 0, 0);
        acc2 = __builtin_amdgcn_mfma_f32_16x16x32_bf16(av, b2, acc2, 0, 0, 0);
        acc3 = __builtin_amdgcn_mfma_f32_16x16x32_bf16(av, b3, acc3, 0, 0, 0);
    }

    // C/D layout: row = (lane>>4)*4 + r (within 16-row tile), col = lane&15
    const int rbase = blockIdx.y * 64 + wave * 16 + (lane >> 4) * 4;
    float* crow = C + (size_t)z * M * N;
    #pragma unroll
    for (int r = 0; r < 4; r++) {
        float* cp = crow + (size_t)(rbase + r) * N + nbase + l15;
        cp[0]  = acc0[r];
        cp[16] = acc1[r];
        cp[32] = acc2[r];
        cp[48] = acc3[r];
    }
}

// ---------------------------------------------------------------------------
// LSTM pointwise: gates = sum_{z<Z} gp[z] (+ xg if non-null) + b_ih + b_hh;
// c' = sig(f)*c + sig(i)*tanh(g); h' = sig(o)*tanh(c'); also emit bf16 h'.
// gp: [Z][64][4096], xg: [64][4096] (chunk-step slice)
// ---------------------------------------------------------------------------
__global__ __launch_bounds__(256) void lstm_pointwise(
    const float* __restrict__ gp, int Z, const float* __restrict__ xg,
    const float* __restrict__ b_ih, const float* __restrict__ b_hh,
    float* __restrict__ c, float* __restrict__ h, ushort* __restrict__ h_bf)
{
    const int idx = blockIdx.x * 256 + threadIdx.x;   // 0..65535
    const int b = idx >> 10;
    const int j = idx & 1023;
    float ig = b_ih[j]        + b_hh[j];
    float fg = b_ih[j + 1024] + b_hh[j + 1024];
    float gg = b_ih[j + 2048] + b_hh[j + 2048];
    float og = b_ih[j + 3072] + b_hh[j + 3072];
    if (xg) {
        const float* x = xg + (size_t)b * NG;
        ig += x[j]; fg += x[j + 1024]; gg += x[j + 2048]; og += x[j + 3072];
    }
    for (int z = 0; z < Z; z++) {
        const float* g = gp + (size_t)(z * 64 + b) * NG;
        ig += g[j]; fg += g[j + 1024]; gg += g[j + 2048]; og += g[j + 3072];
    }
    const float si = 1.f / (1.f + expf(-ig));
    const float sf = 1.f / (1.f + expf(-fg));
    const float so = 1.f / (1.f + expf(-og));
    const float tg = tanhf(gg);
    const float cn = sf * c[idx] + si * tg;
    c[idx] = cn;
    const float hn = so * tanhf(cn);
    h[idx] = hn;
    h_bf[idx] = bf16_rne(hn);
}

// ---------------------------------------------------------------------------
// Projection epilogue: sum 8 split-K partials + bias, log_softmax, write fp32
// out and bf16 copy (next decode input).  lp: [8][64][1024]
// ---------------------------------------------------------------------------
__global__ __launch_bounds__(256) void proj_softmax(
    const float* __restrict__ lp, const float* __restrict__ b_out,
    float* __restrict__ out, ushort* __restrict__ out_bf)
{
    const int b = blockIdx.x;
    __shared__ float row[1024];
    __shared__ float red[256];
    const int tid = threadIdx.x;

    for (int j = tid; j < 1024; j += 256) {
        float v = b_out[j];
        #pragma unroll
        for (int z = 0; z < 8; z++)
            v += lp[(size_t)(z * 64 + b) * 1024 + j];
        row[j] = v;
    }
    __syncthreads();

    float m = -INFINITY;
    for (int j = tid; j < 1024; j += 256) m = fmaxf(m, row[j]);
    red[tid] = m; __syncthreads();
    for (int st = 128; st > 0; st >>= 1) {
        if (tid < st) red[tid] = fmaxf(red[tid], red[tid + st]);
        __syncthreads();
    }
    m = red[0];
    __syncthreads();

    float s = 0.f;
    for (int j = tid; j < 1024; j += 256) s += expf(row[j] - m);
    red[tid] = s; __syncthreads();
    for (int st = 128; st > 0; st >>= 1) {
        if (tid < st) red[tid] += red[tid + st];
        __syncthreads();
    }
    const float lse = m + logf(red[0]);

    for (int j = tid; j < 1024; j += 256) {
        const float v = row[j] - lse;
        out[(size_t)b * 1024 + j] = v;
        out_bf[(size_t)b * 1024 + j] = bf16_rne(v);
    }
}

// ---------------------------------------------------------------------------
__global__ __launch_bounds__(256) void copy2(
    const float* __restrict__ a, const float* __restrict__ b,
    float* __restrict__ da, float* __restrict__ db, int n)
{
    const int i = blockIdx.x * 256 + threadIdx.x;
    if (i < n) { da[i] = a[i]; db[i] = b[i]; }
}

// ---------------------------------------------------------------------------
extern "C" void kernel_launch(void* const* d_in, const int* in_sizes, int n_in,
                              void* d_out, int out_size, void* d_ws, size_t ws_size,
                              hipStream_t stream)
{
    const float* input = (const float*)d_in[0];   // [128,64,1024]
    const float* h0    = (const float*)d_in[1];
    const float* c0    = (const float*)d_in[2];
    const float* W_ih  = (const float*)d_in[3];   // [4096,1024]
    const float* W_hh  = (const float*)d_in[4];   // [4096,1024]
    const float* b_ih  = (const float*)d_in[5];
    const float* b_hh  = (const float*)d_in[6];
    const float* W_out = (const float*)d_in[7];   // [1024,1024]
    const float* b_out = (const float*)d_in[8];
    float* out = (float*)d_out;                   // [32,64,1024] + h + c

    // workspace carve-up (bytes)
    char* w = (char*)d_ws;
    ushort* Wih_bf  = (ushort*)(w);                       // 8,388,608
    ushort* Whh_bf  = (ushort*)(w + 8388608);             // 8,388,608
    ushort* Wout_bf = (ushort*)(w + 16777216);            // 2,097,152
    ushort* Xc_bf   = (ushort*)(w + 18874368);            // 2,097,152
    float*  Xg      = (float*) (w + 20971520);            // 16,777,216
    float*  gpart   = (float*) (w + 37748736);            // 8,388,608
    float*  ppart   = (float*) (w + 46137344);            // 2,097,152
    float*  hbuf    = (float*) (w + 48234496);            // 262,144
    float*  cbuf    = (float*) (w + 48496640);            // 262,144
    ushort* h_bf    = (ushort*)(w + 48758784);            // 131,072
    ushort* xd_bf   = (ushort*)(w + 48889856);            // 131,072

    const int NE = BATCH * HD;  // 65536

    // one-time converts
    f32_to_bf16<<<dim3(4096), dim3(256), 0, stream>>>(W_ih,  Wih_bf,  NG * HD);
    f32_to_bf16<<<dim3(4096), dim3(256), 0, stream>>>(W_hh,  Whh_bf,  NG * HD);
    f32_to_bf16<<<dim3(1024), dim3(256), 0, stream>>>(W_out, Wout_bf, HD * HD);
    init_state <<<dim3(NE / 256), dim3(256), 0, stream>>>(h0, c0, hbuf, cbuf, h_bf);

    // ---- encode: 8 chunks of 16 steps; hoisted x@W_ih^T per chunk ----
    for (int ch = 0; ch < SEQ / CH; ch++) {
        f32_to_bf16<<<dim3(1024), dim3(256), 0, stream>>>(
            input + (size_t)ch * CH * NE, Xc_bf, CH * BATCH * HD);
        // Xg[1024][4096] = Xc_bf[1024][1024] @ W_ih^T
        gemm_bt_mfma<<<dim3(NG / 64, (CH * BATCH) / 64, 1), dim3(256), 0, stream>>>(
            Xc_bf, Wih_bf, nullptr, nullptr, Xg, NG, HD, CH * BATCH);
        for (int s = 0; s < CH; s++) {
            gemm_bt_mfma<<<dim3(NG / 64, 1, 4), dim3(256), 0, stream>>>(
                h_bf, Whh_bf, nullptr, nullptr, gpart, NG, 256, BATCH);
            lstm_pointwise<<<dim3(NE / 256), dim3(256), 0, stream>>>(
                gpart, 4, Xg + (size_t)s * BATCH * NG, b_ih, b_hh, cbuf, hbuf, h_bf);
        }
    }

    // out0
    gemm_bt_mfma<<<dim3(HD / 64, 1, 8), dim3(256), 0, stream>>>(
        h_bf, Wout_bf, nullptr, nullptr, ppart, HD, 128, BATCH);
    proj_softmax<<<dim3(BATCH), dim3(256), 0, stream>>>(ppart, b_out, out, xd_bf);

    // ---- decode: 31 steps ----
    for (int d = 1; d < TOUT; d++) {
        // gates = xd@W_ih^T (z 0..3) + h@W_hh^T (z 4..7), ksl=256
        gemm_bt_mfma<<<dim3(NG / 64, 1, 8), dim3(256), 0, stream>>>(
            xd_bf, Wih_bf, h_bf, Whh_bf, gpart, NG, 256, BATCH);
        lstm_pointwise<<<dim3(NE / 256), dim3(256), 0, stream>>>(
            gpart, 8, nullptr, b_ih, b_hh, cbuf, hbuf, h_bf);
        gemm_bt_mfma<<<dim3(HD / 64, 1, 8), dim3(256), 0, stream>>>(
            h_bf, Wout_bf, nullptr, nullptr, ppart, HD, 128, BATCH);
        proj_softmax<<<dim3(BATCH), dim3(256), 0, stream>>>(
            ppart, b_out, out + (size_t)d * NE, xd_bf);
    }

    // final h, c
    copy2<<<dim3(NE / 256), dim3(256), 0, stream>>>(
        hbuf, cbuf, out + (size_t)TOUT * NE, out + (size_t)(TOUT + 1) * NE, NE);
}